// Round 3
// baseline (3249.289 us; speedup 1.0000x reference)
//
#include <hip/hip_runtime.h>

#define DIM 128

// ---------------------------------------------------------------------------
// Phase 1: edge-parallel scatter-add with fp32 atomics.
// NOTE: harness uploads integer inputs as int32 — edge_index is const int*.
// Bidirectional: agg[dst] += x[src]; agg[src] += x[dst]; deg both +=1.
// One thread = one float4 chunk (4 feats) of one edge; 32 chunks/edge.
// agg lives in d_out (same size as the output), deg in d_ws (400 KB).
// ---------------------------------------------------------------------------
__global__ __launch_bounds__(256) void scatter_kernel(
    const float* __restrict__ x,
    const int* __restrict__ ei,         // [2, E] int32 on device
    float* __restrict__ agg,            // = d_out, zeroed
    float* __restrict__ deg,            // [N], zeroed
    int E)
{
    int gid = blockIdx.x * blockDim.x + threadIdx.x;
    int e = gid >> 5;
    int c = gid & 31;                   // float4 chunk 0..31
    if (e >= E) return;
    int src = ei[e];
    int dst = ei[E + e];

    const float4* x4 = (const float4*)x;
    float4 vs = x4[(size_t)src * 32 + c];   // x[src] chunk
    float4 vd = x4[(size_t)dst * 32 + c];   // x[dst] chunk

    float* ad  = agg + (size_t)dst * DIM + c * 4;
    float* as_ = agg + (size_t)src * DIM + c * 4;
    atomicAdd(ad + 0, vs.x); atomicAdd(ad + 1, vs.y);
    atomicAdd(ad + 2, vs.z); atomicAdd(ad + 3, vs.w);
    atomicAdd(as_ + 0, vd.x); atomicAdd(as_ + 1, vd.y);
    atomicAdd(as_ + 2, vd.z); atomicAdd(as_ + 3, vd.w);

    if (c == 0) {
        atomicAdd(deg + dst, 1.0f);
        atomicAdd(deg + src, 1.0f);
    }
}

// ---------------------------------------------------------------------------
// Phase 2: fused out = relu(x @ Ws^T + (agg/max(deg,1)) @ Wn^T + bias)
// agg aliases out: each block reads its own 32 rows into LDS first, then
// overwrites them in the epilogue — no cross-block hazard (row ownership).
// Block: 256 threads, tile 32 rows x 128 cols, per-thread 4x4.
// ---------------------------------------------------------------------------
__global__ __launch_bounds__(256) void gemm_kernel(
    const float* __restrict__ x,
    const float* __restrict__ agg,      // = d_out contents (aggregated sums)
    const float* __restrict__ deg,
    const float* __restrict__ Ws,
    const float* __restrict__ Wn,
    const float* __restrict__ bias,
    float* __restrict__ out,            // = d_out
    int N)
{
    __shared__ float xs[32][DIM];
    __shared__ float as[32][DIM];

    const int r0 = blockIdx.x * 32;
    const int tid = threadIdx.x;

    // Cooperative load: 32 rows x 32 float4, 4 per thread. Normalize agg here.
    for (int i = tid; i < 32 * 32; i += 256) {
        int r = i >> 5, c4 = i & 31;
        int row = r0 + r;
        if (row < N) {
            float4 v = ((const float4*)x)[(size_t)row * 32 + c4];
            *(float4*)&xs[r][c4 * 4] = v;
            float inv = 1.0f / fmaxf(deg[row], 1.0f);
            float4 a = ((const float4*)agg)[(size_t)row * 32 + c4];
            a.x *= inv; a.y *= inv; a.z *= inv; a.w *= inv;
            *(float4*)&as[r][c4 * 4] = a;
        }
    }
    __syncthreads();

    const int cg = tid & 31;   // cols cg*4 .. cg*4+3
    const int rg = tid >> 5;   // rows rg*4 .. rg*4+3

    float acc[4][4] = {};
    const float4* Ws4 = (const float4*)Ws;
    const float4* Wn4 = (const float4*)Wn;

    #pragma unroll 4
    for (int k4 = 0; k4 < 32; ++k4) {
        float4 xv[4], av[4], wsv[4], wnv[4];
        #pragma unroll
        for (int i = 0; i < 4; ++i) {
            xv[i] = *(const float4*)&xs[rg * 4 + i][k4 * 4];
            av[i] = *(const float4*)&as[rg * 4 + i][k4 * 4];
        }
        #pragma unroll
        for (int j = 0; j < 4; ++j) {
            wsv[j] = Ws4[(size_t)(cg * 4 + j) * 32 + k4];
            wnv[j] = Wn4[(size_t)(cg * 4 + j) * 32 + k4];
        }
        #pragma unroll
        for (int i = 0; i < 4; ++i) {
            #pragma unroll
            for (int j = 0; j < 4; ++j) {
                acc[i][j] += xv[i].x * wsv[j].x + xv[i].y * wsv[j].y
                           + xv[i].z * wsv[j].z + xv[i].w * wsv[j].w
                           + av[i].x * wnv[j].x + av[i].y * wnv[j].y
                           + av[i].z * wnv[j].z + av[i].w * wnv[j].w;
            }
        }
    }

    float4 b = *(const float4*)&bias[cg * 4];
    #pragma unroll
    for (int i = 0; i < 4; ++i) {
        int row = r0 + rg * 4 + i;
        if (row < N) {
            float4 v;
            v.x = fmaxf(acc[i][0] + b.x, 0.0f);
            v.y = fmaxf(acc[i][1] + b.y, 0.0f);
            v.z = fmaxf(acc[i][2] + b.z, 0.0f);
            v.w = fmaxf(acc[i][3] + b.w, 0.0f);
            ((float4*)out)[(size_t)row * 32 + cg] = v;
        }
    }
}

extern "C" void kernel_launch(void* const* d_in, const int* in_sizes, int n_in,
                              void* d_out, int out_size, void* d_ws, size_t ws_size,
                              hipStream_t stream) {
    const float* x        = (const float*)d_in[0];
    const int* ei         = (const int*)d_in[1];   // int32 on device (harness converts)
    // d_in[2] = num_nodes scalar (unused; derived from in_sizes)
    const float* Ws       = (const float*)d_in[3];
    const float* Wn       = (const float*)d_in[4];
    const float* bias     = (const float*)d_in[5];
    float* out            = (float*)d_out;

    const int N = in_sizes[0] / DIM;      // 100000
    const int E = in_sizes[1] / 2;        // 800000

    float* agg = out;                     // accumulate agg directly in d_out
    float* deg = (float*)d_ws;            // [N] fp32, 400 KB

    // Zero accumulators (harness re-poisons d_out/d_ws to 0xAA each call).
    hipMemsetAsync(out, 0, (size_t)out_size * sizeof(float), stream);
    hipMemsetAsync(deg, 0, (size_t)N * sizeof(float), stream);

    // Scatter: E edges x 32 chunks.
    long long sthreads = (long long)E * 32;
    int sblocks = (int)((sthreads + 255) / 256);
    scatter_kernel<<<sblocks, 256, 0, stream>>>(x, ei, agg, deg, E);

    // Fused dual-GEMM + bias + relu (reads agg from d_out, overwrites d_out).
    int gblocks = (N + 31) / 32;
    gemm_kernel<<<gblocks, 256, 0, stream>>>(x, agg, deg, Ws, Wn, bias, out, N);
}

// Round 4
// 1004.051 us; speedup vs baseline: 3.2362x; 3.2362x over previous
//
#include <hip/hip_runtime.h>

#define DIM 128

// ===========================================================================
// CSR path: count degrees -> exclusive scan -> fill adjacency -> gather.
// Replaces 204.8M scattered fp32 atomics (3.25 GB HBM write traffic, round 3)
// with 6.4M int atomics on L2-resident counters + one coalesced write pass.
// ===========================================================================

__global__ __launch_bounds__(256) void count_kernel(
    const int* __restrict__ ei, int* __restrict__ deg, int E)
{
    int e = blockIdx.x * blockDim.x + threadIdx.x;
    if (e >= E) return;
    atomicAdd(deg + ei[e], 1);        // src gains dst as neighbor
    atomicAdd(deg + ei[E + e], 1);    // dst gains src as neighbor
}

// Single-block exclusive scan over deg[N] -> rowptr[N+1], cursor[N].
__global__ __launch_bounds__(1024) void scan_kernel(
    const int* __restrict__ deg, int* __restrict__ rowptr,
    int* __restrict__ cursor, int N)
{
    __shared__ int sums[1024];
    const int t = threadIdx.x;
    const int chunk = (N + 1023) >> 10;
    const int lo = t * chunk;
    const int hi = min(lo + chunk, N);

    int s = 0;
    for (int i = lo; i < hi; ++i) s += deg[i];
    sums[t] = s;
    __syncthreads();

    // Hillis-Steele inclusive scan over the 1024 partial sums.
    for (int off = 1; off < 1024; off <<= 1) {
        int v = (t >= off) ? sums[t - off] : 0;
        __syncthreads();
        sums[t] += v;
        __syncthreads();
    }

    int run = (t == 0) ? 0 : sums[t - 1];
    for (int i = lo; i < hi; ++i) {
        rowptr[i] = run;
        cursor[i] = run;
        run += deg[i];
    }
    if (t == 1023) rowptr[N] = sums[1023];
}

__global__ __launch_bounds__(256) void fill_kernel(
    const int* __restrict__ ei, int* __restrict__ cursor,
    int* __restrict__ col, int E)
{
    int e = blockIdx.x * blockDim.x + threadIdx.x;
    if (e >= E) return;
    int s = ei[e];
    int d = ei[E + e];
    int p0 = atomicAdd(cursor + d, 1);  col[p0] = s;  // d gathers from s
    int p1 = atomicAdd(cursor + s, 1);  col[p1] = d;  // s gathers from d
}

// One wave per node: lane L owns float2 features [2L, 2L+1].
// Neighbor indices broadcast via __shfl (1 coalesced col load per 64 nbrs).
__global__ __launch_bounds__(256) void gather_kernel(
    const float* __restrict__ x,
    const int* __restrict__ rowptr,
    const int* __restrict__ deg,
    const int* __restrict__ col,
    float* __restrict__ agg,            // = d_out; every row fully written
    int N)
{
    const int n = blockIdx.x * 4 + (threadIdx.x >> 6);
    if (n >= N) return;
    const int lane = threadIdx.x & 63;

    const int start = rowptr[n];
    const int cnt = deg[n];
    const float2* x2 = (const float2*)x;

    float2 acc = make_float2(0.0f, 0.0f);
    for (int j0 = 0; j0 < cnt; j0 += 64) {
        int idx = 0;
        if (j0 + lane < cnt) idx = col[start + j0 + lane];
        const int m = min(64, cnt - j0);
        int jj = 0;
        for (; jj + 4 <= m; jj += 4) {   // 4 independent row-loads in flight
            int n0 = __shfl(idx, jj);
            int n1 = __shfl(idx, jj + 1);
            int n2 = __shfl(idx, jj + 2);
            int n3 = __shfl(idx, jj + 3);
            float2 v0 = x2[(size_t)n0 * 64 + lane];
            float2 v1 = x2[(size_t)n1 * 64 + lane];
            float2 v2 = x2[(size_t)n2 * 64 + lane];
            float2 v3 = x2[(size_t)n3 * 64 + lane];
            acc.x += v0.x + v1.x + v2.x + v3.x;
            acc.y += v0.y + v1.y + v2.y + v3.y;
        }
        for (; jj < m; ++jj) {
            int nb = __shfl(idx, jj);
            float2 v = x2[(size_t)nb * 64 + lane];
            acc.x += v.x; acc.y += v.y;
        }
    }

    const float inv = 1.0f / fmaxf((float)cnt, 1.0f);
    acc.x *= inv; acc.y *= inv;
    ((float2*)agg)[(size_t)n * 64 + lane] = acc;
}

// ===========================================================================
// Fallback (ws too small for CSR): round-3 atomic scatter, float deg.
// ===========================================================================
__global__ __launch_bounds__(256) void scatter_kernel(
    const float* __restrict__ x, const int* __restrict__ ei,
    float* __restrict__ agg, float* __restrict__ deg, int E)
{
    int gid = blockIdx.x * blockDim.x + threadIdx.x;
    int e = gid >> 5;
    int c = gid & 31;
    if (e >= E) return;
    int src = ei[e];
    int dst = ei[E + e];
    const float4* x4 = (const float4*)x;
    float4 vs = x4[(size_t)src * 32 + c];
    float4 vd = x4[(size_t)dst * 32 + c];
    float* ad  = agg + (size_t)dst * DIM + c * 4;
    float* as_ = agg + (size_t)src * DIM + c * 4;
    atomicAdd(ad + 0, vs.x); atomicAdd(ad + 1, vs.y);
    atomicAdd(ad + 2, vs.z); atomicAdd(ad + 3, vs.w);
    atomicAdd(as_ + 0, vd.x); atomicAdd(as_ + 1, vd.y);
    atomicAdd(as_ + 2, vd.z); atomicAdd(as_ + 3, vd.w);
    if (c == 0) {
        atomicAdd(deg + dst, 1.0f);
        atomicAdd(deg + src, 1.0f);
    }
}

__global__ __launch_bounds__(256) void norm_kernel(   // fallback: agg /= max(deg,1)
    float* __restrict__ agg, const float* __restrict__ deg, int N)
{
    int gid = blockIdx.x * blockDim.x + threadIdx.x;
    int n = gid >> 5, c = gid & 31;
    if (n >= N) return;
    float inv = 1.0f / fmaxf(deg[n], 1.0f);
    float4* a4 = (float4*)agg + (size_t)n * 32 + c;
    float4 a = *a4;
    a.x *= inv; a.y *= inv; a.z *= inv; a.w *= inv;
    *a4 = a;
}

// ===========================================================================
// Phase 2: out = relu(x @ Ws^T + agg @ Wn^T + bias). agg pre-normalized,
// aliases d_out (row ownership: each block reads its rows to LDS, then
// overwrites them). 256 thr, 32x128 tile, 4x4 per thread.
// ===========================================================================
__global__ __launch_bounds__(256) void gemm_kernel(
    const float* __restrict__ x,
    const float* __restrict__ agg,
    const float* __restrict__ Ws,
    const float* __restrict__ Wn,
    const float* __restrict__ bias,
    float* __restrict__ out,
    int N)
{
    __shared__ float xs[32][DIM];
    __shared__ float as[32][DIM];

    const int r0 = blockIdx.x * 32;
    const int tid = threadIdx.x;

    for (int i = tid; i < 32 * 32; i += 256) {
        int r = i >> 5, c4 = i & 31;
        int row = r0 + r;
        if (row < N) {
            *(float4*)&xs[r][c4 * 4] = ((const float4*)x)[(size_t)row * 32 + c4];
            *(float4*)&as[r][c4 * 4] = ((const float4*)agg)[(size_t)row * 32 + c4];
        }
    }
    __syncthreads();

    const int cg = tid & 31;
    const int rg = tid >> 5;

    float acc[4][4] = {};
    const float4* Ws4 = (const float4*)Ws;
    const float4* Wn4 = (const float4*)Wn;

    #pragma unroll 4
    for (int k4 = 0; k4 < 32; ++k4) {
        float4 xv[4], av[4], wsv[4], wnv[4];
        #pragma unroll
        for (int i = 0; i < 4; ++i) {
            xv[i] = *(const float4*)&xs[rg * 4 + i][k4 * 4];
            av[i] = *(const float4*)&as[rg * 4 + i][k4 * 4];
        }
        #pragma unroll
        for (int j = 0; j < 4; ++j) {
            wsv[j] = Ws4[(size_t)(cg * 4 + j) * 32 + k4];
            wnv[j] = Wn4[(size_t)(cg * 4 + j) * 32 + k4];
        }
        #pragma unroll
        for (int i = 0; i < 4; ++i) {
            #pragma unroll
            for (int j = 0; j < 4; ++j) {
                acc[i][j] += xv[i].x * wsv[j].x + xv[i].y * wsv[j].y
                           + xv[i].z * wsv[j].z + xv[i].w * wsv[j].w
                           + av[i].x * wnv[j].x + av[i].y * wnv[j].y
                           + av[i].z * wnv[j].z + av[i].w * wnv[j].w;
            }
        }
    }

    float4 b = *(const float4*)&bias[cg * 4];
    #pragma unroll
    for (int i = 0; i < 4; ++i) {
        int row = r0 + rg * 4 + i;
        if (row < N) {
            float4 v;
            v.x = fmaxf(acc[i][0] + b.x, 0.0f);
            v.y = fmaxf(acc[i][1] + b.y, 0.0f);
            v.z = fmaxf(acc[i][2] + b.z, 0.0f);
            v.w = fmaxf(acc[i][3] + b.w, 0.0f);
            ((float4*)out)[(size_t)row * 32 + cg] = v;
        }
    }
}

extern "C" void kernel_launch(void* const* d_in, const int* in_sizes, int n_in,
                              void* d_out, int out_size, void* d_ws, size_t ws_size,
                              hipStream_t stream) {
    const float* x    = (const float*)d_in[0];
    const int* ei     = (const int*)d_in[1];   // int32 on device (harness converts)
    const float* Ws   = (const float*)d_in[3];
    const float* Wn   = (const float*)d_in[4];
    const float* bias = (const float*)d_in[5];
    float* out        = (float*)d_out;

    const int N = in_sizes[0] / DIM;      // 100000
    const int E = in_sizes[1] / 2;        // 800000
    float* agg = out;                     // agg accumulated in d_out

    const size_t csr_bytes = ((size_t)N * 3 + 1 + (size_t)2 * E) * sizeof(int);

    if (ws_size >= csr_bytes) {
        // ---- CSR gather path ----
        int* deg    = (int*)d_ws;             // [N]
        int* rowptr = deg + N;                // [N+1]
        int* cursor = rowptr + N + 1;         // [N]
        int* col    = cursor + N;             // [2E]

        hipMemsetAsync(deg, 0, (size_t)N * sizeof(int), stream);

        int eb = (E + 255) / 256;
        count_kernel<<<eb, 256, 0, stream>>>(ei, deg, E);
        scan_kernel<<<1, 1024, 0, stream>>>(deg, rowptr, cursor, N);
        fill_kernel<<<eb, 256, 0, stream>>>(ei, cursor, col, E);
        gather_kernel<<<(N + 3) / 4, 256, 0, stream>>>(x, rowptr, deg, col, agg, N);
    } else {
        // ---- fallback: atomic scatter (round-3 proven) ----
        float* deg = (float*)d_ws;            // [N]
        hipMemsetAsync(out, 0, (size_t)out_size * sizeof(float), stream);
        hipMemsetAsync(deg, 0, (size_t)N * sizeof(float), stream);
        long long sthreads = (long long)E * 32;
        scatter_kernel<<<(int)((sthreads + 255) / 256), 256, 0, stream>>>(x, ei, agg, deg, E);
        long long nthreads = (long long)N * 32;
        norm_kernel<<<(int)((nthreads + 255) / 256), 256, 0, stream>>>(agg, deg, N);
    }

    gemm_kernel<<<(N + 31) / 32, 256, 0, stream>>>(x, agg, Ws, Wn, bias, out, N);
}

// Round 5
// 687.939 us; speedup vs baseline: 4.7232x; 1.4595x over previous
//
#include <hip/hip_runtime.h>

#define DIM 128

typedef __attribute__((ext_vector_type(8))) short bf16x8;
typedef __attribute__((ext_vector_type(4))) float f32x4;

__device__ inline short f2bf(float f) {
    unsigned u = __builtin_bit_cast(unsigned, f);
    return (short)((u + 0x8000u) >> 16);   // round-half-up to bf16
}

// ===========================================================================
// CSR build: count degrees -> exclusive scan -> fill adjacency.
// ===========================================================================
__global__ __launch_bounds__(256) void count_kernel(
    const int* __restrict__ ei, int* __restrict__ deg, int E)
{
    int e = blockIdx.x * blockDim.x + threadIdx.x;
    if (e >= E) return;
    atomicAdd(deg + ei[e], 1);
    atomicAdd(deg + ei[E + e], 1);
}

__global__ __launch_bounds__(1024) void scan_kernel(
    const int* __restrict__ deg, int* __restrict__ rowptr,
    int* __restrict__ cursor, int N)
{
    __shared__ int sums[1024];
    const int t = threadIdx.x;
    const int chunk = (N + 1023) >> 10;
    const int lo = t * chunk;
    const int hi = min(lo + chunk, N);

    int s = 0;
    for (int i = lo; i < hi; ++i) s += deg[i];
    sums[t] = s;
    __syncthreads();
    for (int off = 1; off < 1024; off <<= 1) {
        int v = (t >= off) ? sums[t - off] : 0;
        __syncthreads();
        sums[t] += v;
        __syncthreads();
    }
    int run = (t == 0) ? 0 : sums[t - 1];
    for (int i = lo; i < hi; ++i) {
        rowptr[i] = run;
        cursor[i] = run;
        run += deg[i];
    }
    if (t == 1023) rowptr[N] = sums[1023];
}

__global__ __launch_bounds__(256) void fill_kernel(
    const int* __restrict__ ei, int* __restrict__ cursor,
    int* __restrict__ col, int E)
{
    int e = blockIdx.x * blockDim.x + threadIdx.x;
    if (e >= E) return;
    int s = ei[e];
    int d = ei[E + e];
    int p0 = atomicAdd(cursor + d, 1);  col[p0] = s;
    int p1 = atomicAdd(cursor + s, 1);  col[p1] = d;
}

// One wave per node: lane L owns float2 features [2L, 2L+1].
__global__ __launch_bounds__(256) void gather_kernel(
    const float* __restrict__ x,
    const int* __restrict__ rowptr,
    const int* __restrict__ deg,
    const int* __restrict__ col,
    float* __restrict__ agg,            // = d_out
    int N)
{
    const int n = blockIdx.x * 4 + (threadIdx.x >> 6);
    if (n >= N) return;
    const int lane = threadIdx.x & 63;

    const int start = rowptr[n];
    const int cnt = deg[n];
    const float2* x2 = (const float2*)x;

    float2 acc = make_float2(0.0f, 0.0f);
    for (int j0 = 0; j0 < cnt; j0 += 64) {
        int idx = 0;
        if (j0 + lane < cnt) idx = col[start + j0 + lane];
        const int m = min(64, cnt - j0);
        int jj = 0;
        for (; jj + 4 <= m; jj += 4) {
            int n0 = __shfl(idx, jj);
            int n1 = __shfl(idx, jj + 1);
            int n2 = __shfl(idx, jj + 2);
            int n3 = __shfl(idx, jj + 3);
            float2 v0 = x2[(size_t)n0 * 64 + lane];
            float2 v1 = x2[(size_t)n1 * 64 + lane];
            float2 v2 = x2[(size_t)n2 * 64 + lane];
            float2 v3 = x2[(size_t)n3 * 64 + lane];
            acc.x += v0.x + v1.x + v2.x + v3.x;
            acc.y += v0.y + v1.y + v2.y + v3.y;
        }
        for (; jj < m; ++jj) {
            int nb = __shfl(idx, jj);
            float2 v = x2[(size_t)nb * 64 + lane];
            acc.x += v.x; acc.y += v.y;
        }
    }
    const float inv = 1.0f / fmaxf((float)cnt, 1.0f);
    acc.x *= inv; acc.y *= inv;
    ((float2*)agg)[(size_t)n * 64 + lane] = acc;
}

// ===========================================================================
// W pre-convert: Wb[n][k] (bf16, [128][256]) = k<128 ? Ws[n][k] : Wn[n][k-128]
// ===========================================================================
__global__ __launch_bounds__(256) void wconv_kernel(
    const float* __restrict__ Ws, const float* __restrict__ Wn,
    unsigned short* __restrict__ Wb)
{
    int i = blockIdx.x * 256 + threadIdx.x;       // 0..32767
    int n = i >> 8, k = i & 255;
    float v = (k < DIM) ? Ws[n * DIM + k] : Wn[n * DIM + (k - DIM)];
    Wb[i] = (unsigned short)f2bf(v);
}

// ===========================================================================
// MFMA GEMM: out = relu([x|agg] @ Wb^T + bias), K=256, bf16 in / fp32 acc.
// Block = 4 waves x 16 rows = 64 rows; each wave does 8 n-tiles of 16x16x32.
// Register-only fragments: lane (m=lane&15, quad=lane>>4) loads 16 contiguous
// bytes per fragment per k-step — A from fp32 global (cvt in-flight), B from
// the L2-resident bf16 W. agg aliases d_out: each wave reads only its own 16
// rows before overwriting them (program-order safe within a wave).
// A/B frag layout m89-verified: A[m=lane&15][k=quad*8+j]; C/D col=lane&15,
// row=quad*4+reg.
// ===========================================================================
__global__ __launch_bounds__(256) void mfma_gemm_kernel(
    const float* __restrict__ x,
    const float* __restrict__ agg,            // = d_out
    const unsigned short* __restrict__ Wb,    // [128][256] bf16
    const float* __restrict__ bias,
    float* __restrict__ out,
    int M)
{
    const int wave = threadIdx.x >> 6;
    const int lane = threadIdx.x & 63;
    const int row0 = blockIdx.x * 64 + wave * 16;
    if (row0 >= M) return;                    // M % 16 == 0: whole waves only
    const int m = lane & 15;
    const int quad = lane >> 4;

    f32x4 acc[8];
    #pragma unroll
    for (int nt = 0; nt < 8; ++nt) acc[nt] = (f32x4){0.f, 0.f, 0.f, 0.f};

    const float* arow_x = x   + (size_t)(row0 + m) * DIM + quad * 8;
    const float* arow_g = agg + (size_t)(row0 + m) * DIM + quad * 8;
    const unsigned short* brow = Wb + (size_t)m * 256 + quad * 8;

    #pragma unroll
    for (int ks = 0; ks < 8; ++ks) {
        const float* ap = (ks < 4) ? (arow_x + ks * 32) : (arow_g + (ks - 4) * 32);
        float4 lo = *(const float4*)(ap);
        float4 hi = *(const float4*)(ap + 4);
        bf16x8 af;
        af[0] = f2bf(lo.x); af[1] = f2bf(lo.y); af[2] = f2bf(lo.z); af[3] = f2bf(lo.w);
        af[4] = f2bf(hi.x); af[5] = f2bf(hi.y); af[6] = f2bf(hi.z); af[7] = f2bf(hi.w);
        #pragma unroll
        for (int nt = 0; nt < 8; ++nt) {
            bf16x8 bf = *(const bf16x8*)(brow + (size_t)nt * 16 * 256 + ks * 32);
            acc[nt] = __builtin_amdgcn_mfma_f32_16x16x32_bf16(af, bf, acc[nt], 0, 0, 0);
        }
    }

    #pragma unroll
    for (int nt = 0; nt < 8; ++nt) {
        int c = nt * 16 + m;
        float b = bias[c];
        #pragma unroll
        for (int r = 0; r < 4; ++r) {
            int row = row0 + quad * 4 + r;
            out[(size_t)row * DIM + c] = fmaxf(acc[nt][r] + b, 0.0f);
        }
    }
}

// ===========================================================================
// Fallback fp32 GEMM (round-4 proven) for ws-too-small case.
// ===========================================================================
__global__ __launch_bounds__(256) void gemm_kernel(
    const float* __restrict__ x, const float* __restrict__ agg,
    const float* __restrict__ Ws, const float* __restrict__ Wn,
    const float* __restrict__ bias, float* __restrict__ out, int N)
{
    __shared__ float xs[32][DIM];
    __shared__ float as[32][DIM];
    const int r0 = blockIdx.x * 32;
    const int tid = threadIdx.x;
    for (int i = tid; i < 32 * 32; i += 256) {
        int r = i >> 5, c4 = i & 31;
        int row = r0 + r;
        if (row < N) {
            *(float4*)&xs[r][c4 * 4] = ((const float4*)x)[(size_t)row * 32 + c4];
            *(float4*)&as[r][c4 * 4] = ((const float4*)agg)[(size_t)row * 32 + c4];
        }
    }
    __syncthreads();
    const int cg = tid & 31, rg = tid >> 5;
    float acc[4][4] = {};
    const float4* Ws4 = (const float4*)Ws;
    const float4* Wn4 = (const float4*)Wn;
    #pragma unroll 4
    for (int k4 = 0; k4 < 32; ++k4) {
        float4 xv[4], av[4], wsv[4], wnv[4];
        #pragma unroll
        for (int i = 0; i < 4; ++i) {
            xv[i] = *(const float4*)&xs[rg * 4 + i][k4 * 4];
            av[i] = *(const float4*)&as[rg * 4 + i][k4 * 4];
        }
        #pragma unroll
        for (int j = 0; j < 4; ++j) {
            wsv[j] = Ws4[(size_t)(cg * 4 + j) * 32 + k4];
            wnv[j] = Wn4[(size_t)(cg * 4 + j) * 32 + k4];
        }
        #pragma unroll
        for (int i = 0; i < 4; ++i)
            #pragma unroll
            for (int j = 0; j < 4; ++j)
                acc[i][j] += xv[i].x * wsv[j].x + xv[i].y * wsv[j].y
                           + xv[i].z * wsv[j].z + xv[i].w * wsv[j].w
                           + av[i].x * wnv[j].x + av[i].y * wnv[j].y
                           + av[i].z * wnv[j].z + av[i].w * wnv[j].w;
    }
    float4 b = *(const float4*)&bias[cg * 4];
    #pragma unroll
    for (int i = 0; i < 4; ++i) {
        int row = r0 + rg * 4 + i;
        if (row < N) {
            float4 v;
            v.x = fmaxf(acc[i][0] + b.x, 0.0f);
            v.y = fmaxf(acc[i][1] + b.y, 0.0f);
            v.z = fmaxf(acc[i][2] + b.z, 0.0f);
            v.w = fmaxf(acc[i][3] + b.w, 0.0f);
            ((float4*)out)[(size_t)row * 32 + cg] = v;
        }
    }
}

extern "C" void kernel_launch(void* const* d_in, const int* in_sizes, int n_in,
                              void* d_out, int out_size, void* d_ws, size_t ws_size,
                              hipStream_t stream) {
    const float* x    = (const float*)d_in[0];
    const int* ei     = (const int*)d_in[1];   // int32 on device (harness converts)
    const float* Ws   = (const float*)d_in[3];
    const float* Wn   = (const float*)d_in[4];
    const float* bias = (const float*)d_in[5];
    float* out        = (float*)d_out;

    const int N = in_sizes[0] / DIM;      // 100000
    const int E = in_sizes[1] / 2;        // 800000
    float* agg = out;

    const size_t csr_ints  = (size_t)N * 3 + 1 + (size_t)2 * E;
    const size_t csr_bytes = csr_ints * sizeof(int);
    const size_t wb_bytes  = (size_t)DIM * 256 * sizeof(unsigned short);  // 64 KB

    if (ws_size >= csr_bytes) {
        int* deg    = (int*)d_ws;
        int* rowptr = deg + N;
        int* cursor = rowptr + N + 1;
        int* col    = cursor + N;

        hipMemsetAsync(deg, 0, (size_t)N * sizeof(int), stream);
        int eb = (E + 255) / 256;
        count_kernel<<<eb, 256, 0, stream>>>(ei, deg, E);
        scan_kernel<<<1, 1024, 0, stream>>>(deg, rowptr, cursor, N);
        fill_kernel<<<eb, 256, 0, stream>>>(ei, cursor, col, E);
        gather_kernel<<<(N + 3) / 4, 256, 0, stream>>>(x, rowptr, deg, col, agg, N);

        if (ws_size >= csr_bytes + wb_bytes) {
            unsigned short* Wb = (unsigned short*)(col + (size_t)2 * E);
            wconv_kernel<<<(DIM * 256) / 256, 256, 0, stream>>>(Ws, Wn, Wb);
            mfma_gemm_kernel<<<(N + 63) / 64, 256, 0, stream>>>(x, agg, Wb, bias, out, N);
        } else {
            gemm_kernel<<<(N + 31) / 32, 256, 0, stream>>>(x, agg, Ws, Wn, bias, out, N);
        }
    } else {
        // minimal fallback: should not trigger (round 4 proved ws >= csr_bytes)
        gemm_kernel<<<(N + 31) / 32, 256, 0, stream>>>(x, x, Ws, Wn, bias, out, N);
    }
}

// Round 6
// 482.638 us; speedup vs baseline: 6.7324x; 1.4254x over previous
//
#include <hip/hip_runtime.h>

#define DIM 128
#define SCAN_CHUNK 512   // elements per scan block; nblocks = ceil(N/512) <= 256 for N <= 131072

typedef __attribute__((ext_vector_type(8))) short bf16x8;
typedef __attribute__((ext_vector_type(4))) float f32x4;

__device__ inline short f2bf(float f) {
    unsigned u = __builtin_bit_cast(unsigned, f);
    return (short)((u + 0x8000u) >> 16);   // round-half-up to bf16
}

// ===========================================================================
// CSR build: count degrees -> 3-dispatch parallel exclusive scan -> fill.
// ===========================================================================
__global__ __launch_bounds__(256) void count_kernel(
    const int* __restrict__ ei, int* __restrict__ deg, int E)
{
    int e = blockIdx.x * blockDim.x + threadIdx.x;
    if (e >= E) return;
    atomicAdd(deg + ei[e], 1);
    atomicAdd(deg + ei[E + e], 1);
}

// Pass 1: per-block sums of deg over SCAN_CHUNK-element chunks.
__global__ __launch_bounds__(256) void scan_reduce_kernel(
    const int* __restrict__ deg, int* __restrict__ bsum, int N)
{
    __shared__ int red[256];
    const int t = threadIdx.x;
    const int base = blockIdx.x * SCAN_CHUNK;
    int s = 0;
    int i0 = base + t, i1 = base + 256 + t;
    if (i0 < N) s += deg[i0];
    if (i1 < N) s += deg[i1];
    red[t] = s;
    __syncthreads();
    for (int off = 128; off > 0; off >>= 1) {
        if (t < off) red[t] += red[t + off];
        __syncthreads();
    }
    if (t == 0) bsum[blockIdx.x] = red[0];
}

// Pass 2: one block scans the <=256 block sums -> exclusive offsets.
__global__ __launch_bounds__(256) void scan_offsets_kernel(
    const int* __restrict__ bsum, int* __restrict__ boff,
    int* __restrict__ rowptr, int nblocks, int N)
{
    __shared__ int sums[256];
    const int t = threadIdx.x;
    int v = (t < nblocks) ? bsum[t] : 0;
    sums[t] = v;
    __syncthreads();
    for (int off = 1; off < 256; off <<= 1) {
        int u = (t >= off) ? sums[t - off] : 0;
        __syncthreads();
        sums[t] += u;
        __syncthreads();
    }
    if (t < nblocks) boff[t] = sums[t] - v;   // exclusive
    if (t == 255) rowptr[N] = sums[255];      // total = 2E
}

// Pass 3: per-block exclusive scan of its chunk with global base.
__global__ __launch_bounds__(256) void scan_apply_kernel(
    const int* __restrict__ deg, const int* __restrict__ boff,
    int* __restrict__ rowptr, int* __restrict__ cursor, int N)
{
    __shared__ int sums[256];
    const int t = threadIdx.x;
    const int base = blockIdx.x * SCAN_CHUNK;
    const int i0 = base + t * 2, i1 = i0 + 1;
    int v0 = (i0 < N) ? deg[i0] : 0;
    int v1 = (i1 < N) ? deg[i1] : 0;
    int ts = v0 + v1;
    sums[t] = ts;
    __syncthreads();
    for (int off = 1; off < 256; off <<= 1) {
        int u = (t >= off) ? sums[t - off] : 0;
        __syncthreads();
        sums[t] += u;
        __syncthreads();
    }
    int pos = boff[blockIdx.x] + sums[t] - ts;  // exclusive prefix for i0
    if (i0 < N) { rowptr[i0] = pos;       cursor[i0] = pos; }
    if (i1 < N) { rowptr[i1] = pos + v0;  cursor[i1] = pos + v0; }
}

// Fallback single-block scan (only if nblocks > 256, i.e. N > 131072).
__global__ __launch_bounds__(1024) void scan_kernel(
    const int* __restrict__ deg, int* __restrict__ rowptr,
    int* __restrict__ cursor, int N)
{
    __shared__ int sums[1024];
    const int t = threadIdx.x;
    const int chunk = (N + 1023) >> 10;
    const int lo = t * chunk;
    const int hi = min(lo + chunk, N);
    int s = 0;
    for (int i = lo; i < hi; ++i) s += deg[i];
    sums[t] = s;
    __syncthreads();
    for (int off = 1; off < 1024; off <<= 1) {
        int v = (t >= off) ? sums[t - off] : 0;
        __syncthreads();
        sums[t] += v;
        __syncthreads();
    }
    int run = (t == 0) ? 0 : sums[t - 1];
    for (int i = lo; i < hi; ++i) {
        rowptr[i] = run;
        cursor[i] = run;
        run += deg[i];
    }
    if (t == 1023) rowptr[N] = sums[1023];
}

__global__ __launch_bounds__(256) void fill_kernel(
    const int* __restrict__ ei, int* __restrict__ cursor,
    int* __restrict__ col, int E)
{
    int e = blockIdx.x * blockDim.x + threadIdx.x;
    if (e >= E) return;
    int s = ei[e];
    int d = ei[E + e];
    int p0 = atomicAdd(cursor + d, 1);  col[p0] = s;
    int p1 = atomicAdd(cursor + s, 1);  col[p1] = d;
}

// One wave per node: lane L owns float2 features [2L, 2L+1].
__global__ __launch_bounds__(256) void gather_kernel(
    const float* __restrict__ x,
    const int* __restrict__ rowptr,
    const int* __restrict__ deg,
    const int* __restrict__ col,
    float* __restrict__ agg,            // = d_out
    int N)
{
    const int n = blockIdx.x * 4 + (threadIdx.x >> 6);
    if (n >= N) return;
    const int lane = threadIdx.x & 63;

    const int start = rowptr[n];
    const int cnt = deg[n];
    const float2* x2 = (const float2*)x;

    float2 acc = make_float2(0.0f, 0.0f);
    for (int j0 = 0; j0 < cnt; j0 += 64) {
        int idx = 0;
        if (j0 + lane < cnt) idx = col[start + j0 + lane];
        const int m = min(64, cnt - j0);
        int jj = 0;
        for (; jj + 4 <= m; jj += 4) {
            int n0 = __shfl(idx, jj);
            int n1 = __shfl(idx, jj + 1);
            int n2 = __shfl(idx, jj + 2);
            int n3 = __shfl(idx, jj + 3);
            float2 v0 = x2[(size_t)n0 * 64 + lane];
            float2 v1 = x2[(size_t)n1 * 64 + lane];
            float2 v2 = x2[(size_t)n2 * 64 + lane];
            float2 v3 = x2[(size_t)n3 * 64 + lane];
            acc.x += v0.x + v1.x + v2.x + v3.x;
            acc.y += v0.y + v1.y + v2.y + v3.y;
        }
        for (; jj < m; ++jj) {
            int nb = __shfl(idx, jj);
            float2 v = x2[(size_t)nb * 64 + lane];
            acc.x += v.x; acc.y += v.y;
        }
    }
    const float inv = 1.0f / fmaxf((float)cnt, 1.0f);
    acc.x *= inv; acc.y *= inv;
    ((float2*)agg)[(size_t)n * 64 + lane] = acc;
}

// ===========================================================================
// W pre-convert: Wb[n][k] (bf16, [128][256]) = k<128 ? Ws[n][k] : Wn[n][k-128]
// ===========================================================================
__global__ __launch_bounds__(256) void wconv_kernel(
    const float* __restrict__ Ws, const float* __restrict__ Wn,
    unsigned short* __restrict__ Wb)
{
    int i = blockIdx.x * 256 + threadIdx.x;       // 0..32767
    int n = i >> 8, k = i & 255;
    float v = (k < DIM) ? Ws[n * DIM + k] : Wn[n * DIM + (k - DIM)];
    Wb[i] = (unsigned short)f2bf(v);
}

// ===========================================================================
// MFMA GEMM: out = relu([x|agg] @ Wb^T + bias), K=256, bf16 in / fp32 acc.
// Block = 4 waves x 16 rows; wave does 8 n-tiles of 16x16x32, register-only
// fragments. agg aliases d_out (wave reads its own rows before overwrite).
// ===========================================================================
__global__ __launch_bounds__(256) void mfma_gemm_kernel(
    const float* __restrict__ x,
    const float* __restrict__ agg,            // = d_out
    const unsigned short* __restrict__ Wb,    // [128][256] bf16
    const float* __restrict__ bias,
    float* __restrict__ out,
    int M)
{
    const int wave = threadIdx.x >> 6;
    const int lane = threadIdx.x & 63;
    const int row0 = blockIdx.x * 64 + wave * 16;
    if (row0 >= M) return;
    const int m = lane & 15;
    const int quad = lane >> 4;

    f32x4 acc[8];
    #pragma unroll
    for (int nt = 0; nt < 8; ++nt) acc[nt] = (f32x4){0.f, 0.f, 0.f, 0.f};

    const float* arow_x = x   + (size_t)(row0 + m) * DIM + quad * 8;
    const float* arow_g = agg + (size_t)(row0 + m) * DIM + quad * 8;
    const unsigned short* brow = Wb + (size_t)m * 256 + quad * 8;

    #pragma unroll
    for (int ks = 0; ks < 8; ++ks) {
        const float* ap = (ks < 4) ? (arow_x + ks * 32) : (arow_g + (ks - 4) * 32);
        float4 lo = *(const float4*)(ap);
        float4 hi = *(const float4*)(ap + 4);
        bf16x8 af;
        af[0] = f2bf(lo.x); af[1] = f2bf(lo.y); af[2] = f2bf(lo.z); af[3] = f2bf(lo.w);
        af[4] = f2bf(hi.x); af[5] = f2bf(hi.y); af[6] = f2bf(hi.z); af[7] = f2bf(hi.w);
        #pragma unroll
        for (int nt = 0; nt < 8; ++nt) {
            bf16x8 bf = *(const bf16x8*)(brow + (size_t)nt * 16 * 256 + ks * 32);
            acc[nt] = __builtin_amdgcn_mfma_f32_16x16x32_bf16(af, bf, acc[nt], 0, 0, 0);
        }
    }

    #pragma unroll
    for (int nt = 0; nt < 8; ++nt) {
        int c = nt * 16 + m;
        float b = bias[c];
        #pragma unroll
        for (int r = 0; r < 4; ++r) {
            int row = row0 + quad * 4 + r;
            out[(size_t)row * DIM + c] = fmaxf(acc[nt][r] + b, 0.0f);
        }
    }
}

extern "C" void kernel_launch(void* const* d_in, const int* in_sizes, int n_in,
                              void* d_out, int out_size, void* d_ws, size_t ws_size,
                              hipStream_t stream) {
    const float* x    = (const float*)d_in[0];
    const int* ei     = (const int*)d_in[1];   // int32 on device (harness converts)
    const float* Ws   = (const float*)d_in[3];
    const float* Wn   = (const float*)d_in[4];
    const float* bias = (const float*)d_in[5];
    float* out        = (float*)d_out;

    const int N = in_sizes[0] / DIM;      // 100000
    const int E = in_sizes[1] / 2;        // 800000
    float* agg = out;

    // ws layout: deg[N] | rowptr[N+1] | cursor[N] | col[2E] | Wb[32768 bf16] | bsum[256] | boff[256]
    const size_t csr_ints  = (size_t)N * 3 + 1 + (size_t)2 * E;
    const size_t csr_bytes = csr_ints * sizeof(int);
    const size_t wb_bytes  = (size_t)DIM * 256 * sizeof(unsigned short);  // 64 KB
    const size_t scan_bytes = 512 * sizeof(int);                          // 2 KB

    int* deg    = (int*)d_ws;
    int* rowptr = deg + N;
    int* cursor = rowptr + N + 1;
    int* col    = cursor + N;
    unsigned short* Wb = (unsigned short*)(col + (size_t)2 * E);
    int* bsum   = (int*)(Wb + (size_t)DIM * 256);
    int* boff   = bsum + 256;

    hipMemsetAsync(deg, 0, (size_t)N * sizeof(int), stream);
    int eb = (E + 255) / 256;
    count_kernel<<<eb, 256, 0, stream>>>(ei, deg, E);

    const int nblocks = (N + SCAN_CHUNK - 1) / SCAN_CHUNK;
    if (nblocks <= 256 && ws_size >= csr_bytes + wb_bytes + scan_bytes) {
        scan_reduce_kernel<<<nblocks, 256, 0, stream>>>(deg, bsum, N);
        scan_offsets_kernel<<<1, 256, 0, stream>>>(bsum, boff, rowptr, nblocks, N);
        scan_apply_kernel<<<nblocks, 256, 0, stream>>>(deg, boff, rowptr, cursor, N);
    } else {
        scan_kernel<<<1, 1024, 0, stream>>>(deg, rowptr, cursor, N);
    }

    fill_kernel<<<eb, 256, 0, stream>>>(ei, cursor, col, E);
    gather_kernel<<<(N + 3) / 4, 256, 0, stream>>>(x, rowptr, deg, col, agg, N);

    wconv_kernel<<<(DIM * 256) / 256, 256, 0, stream>>>(Ws, Wn, Wb);
    mfma_gemm_kernel<<<(N + 63) / 64, 256, 0, stream>>>(x, agg, Wb, bias, out, N);
}